// Round 10
// baseline (67.166 us; speedup 1.0000x reference)
//
#include <hip/hip_runtime.h>

// PixelVectorExtractor: x (32,16,128,128) f32 ->
// out (32, 16384, 17, 9) f32 where out[n][h*128+w][c][hl*3+wl] =
//   c==16 ? 1.0f : zero-padded x[n][c][h+hl-1][w+wl-1]
//
// One block per (n, h-quad). Stage input rows h0-1..h0+4 of 16 channels in
// bank-skewed LDS + materialized all-ones channel 16 (halo included). One
// u32-offset descriptor quad (ds_read_b128, block-invariant 612-entry
// pattern) feeds FOUR independent {4x ds_read_b32 -> NT float4 store}
// chains (one per output row), wo shifted by s*RSTRIDE.
//
// R9 fix: output base pointer arithmetic must be in FLOAT units
// (out + base0), not float4 units — R9's version stored 4x out of bounds.

#define NN 32
#define CC 16
#define HH 128
#define WW 128
#define RSTRIDE 140                    // floats per (c,hr) row (mod 32 = 12)
#define RPC 6                          // staged h-rows per channel
#define CSTRIDE (RPC * RSTRIDE + 4)    // 844 floats (mod 32 = 12)
#define NFLOATS (17 * CSTRIDE)         // 14348 floats = 57392 B

typedef float f4 __attribute__((ext_vector_type(4)));

__global__ __launch_bounds__(256) void pve_kernel(const float* __restrict__ x,
                                                  float* __restrict__ out) {
    __shared__ float lds[NFLOATS];
    __shared__ unsigned desc[612];  // byte offsets, 2448 B

    // bijective XCD swizzle: 1024 blocks, 8 XCDs, 128 contiguous per XCD
    unsigned bid = blockIdx.x;
    unsigned swz = (bid & 7u) * 128u + (bid >> 3);
    unsigned n = swz >> 5;    // image
    unsigned hq = swz & 31u;  // row quad
    unsigned h0 = hq * 4u;
    unsigned tid = threadIdx.x;

    // stage first (issue global loads early): 96 rows (hr*16 + c) x 32 f4
#pragma unroll
    for (int j = 0; j < 12; ++j) {
        unsigned li = tid + 256u * j;  // 0..3071
        unsigned row = li >> 5;        // 0..95 = hr*16 + c
        unsigned col = li & 31u;       // float4 column
        unsigned c = row & 15u;
        unsigned hr = row >> 4;        // 0..5
        int hh = (int)h0 + (int)hr - 1;
        f4 v = {0.f, 0.f, 0.f, 0.f};
        if ((unsigned)hh < (unsigned)HH) {
            v = reinterpret_cast<const f4*>(
                    x)[((n * CC + c) * HH + (unsigned)hh) * (WW / 4) + col];
        }
        *reinterpret_cast<f4*>(&lds[c * CSTRIDE + hr * RSTRIDE + 4u + col * 4u]) = v;
    }

    // descriptor table (block-invariant): ii = (dw*17 + c)*9 + p,
    // value = byte offset of (c, hl, 3 + wl + dw); add g*16 + s*560 at use.
    // Uniform for all c: c==16 aliases into the all-ones region.
    for (unsigned ii = tid; ii < 612u; ii += 256u) {
        unsigned p = ii % 9u;
        unsigned t = ii / 9u;
        unsigned c = t % 17u;
        unsigned dw = t / 17u;
        unsigned hl = p / 3u;
        unsigned wl = p - hl * 3u;
        desc[ii] = (c * CSTRIDE + hl * RSTRIDE + 3u + wl + dw) * 4u;
    }

    // ones channel: fill channel 16 region with 1.0f (halo = 1 as well)
    for (unsigned li = tid; li < (unsigned)CSTRIDE; li += 256u)
        lds[16u * CSTRIDE + li] = 1.0f;

    // zero halo pads of the 96 real (c,hr) rows
    if (tid < 96u) {
        unsigned c = tid & 15u, hr = tid >> 4;
        lds[c * CSTRIDE + hr * RSTRIDE + 3] = 0.0f;
        lds[c * CSTRIDE + hr * RSTRIDE + 132] = 0.0f;
    }

    __syncthreads();

    const char* ldsb = reinterpret_cast<const char*>(lds);

    // fused epilogue: 4896 float4 positions, each written to 4 slabs
    unsigned base0 = (n * 16384u + h0 * 128u) * 153u;  // float units
    f4* outp = reinterpret_cast<f4*>(out + base0);
#pragma unroll 2
    for (unsigned q = tid; q < 4896u; q += 256u) {
        unsigned g = q / 153u;  // 4-pixel group (0..31)
        unsigned qm = q - g * 153u;
        unsigned wo = g * 16u;  // byte offset add-on, slab 0
        uint4 d4 = *reinterpret_cast<const uint4*>(&desc[qm * 4u]);
#pragma unroll
        for (unsigned s = 0; s < 4u; ++s) {
            unsigned ws = wo + s * (RSTRIDE * 4u);
            f4 v;
            v.x = *reinterpret_cast<const float*>(ldsb + (d4.x + ws));
            v.y = *reinterpret_cast<const float*>(ldsb + (d4.y + ws));
            v.z = *reinterpret_cast<const float*>(ldsb + (d4.z + ws));
            v.w = *reinterpret_cast<const float*>(ldsb + (d4.w + ws));
            __builtin_nontemporal_store(v, &outp[q + s * 4896u]);
        }
    }
}

extern "C" void kernel_launch(void* const* d_in, const int* in_sizes, int n_in,
                              void* d_out, int out_size, void* d_ws, size_t ws_size,
                              hipStream_t stream) {
    const float* x = (const float*)d_in[0];
    float* out = (float*)d_out;
    pve_kernel<<<NN * HH / 4, 256, 0, stream>>>(x, out);
}

// Round 11
// 65.627 us; speedup vs baseline: 1.0234x; 1.0234x over previous
//
#include <hip/hip_runtime.h>

// PixelVectorExtractor: x (32,16,128,128) f32 ->
// out (32, 16384, 17, 9) f32 where out[n][h*128+w][c][hl*3+wl] =
//   c==16 ? 1.0f : zero-padded x[n][c][h+hl-1][w+wl-1]
//
// FINAL (R8 structure, best measured 65.8 us): one block per (n, h-pair).
// Stage rows h0-1..h0+2 of 16 channels in bank-skewed LDS + materialized
// all-ones channel 16. NT float4 stores (A/B-proven +8.5 us vs regular).
// Fused slab loop: one descriptor ds_read_b128 feeds both output rows
// (two independent {4x ds_read_b32 -> NT store} chains per iteration).

#define NN 32
#define CC 16
#define HH 128
#define WW 128
#define RSTRIDE 140              // floats per (c,hr) row (mod 32 = 12)
#define CSTRIDE 564              // floats per channel (mod 32 = 20)
#define NFLOATS (17 * CSTRIDE)   // 9588 floats = 38352 B

typedef float f4 __attribute__((ext_vector_type(4)));

__global__ __launch_bounds__(256) void pve_kernel(const float* __restrict__ x,
                                                  float* __restrict__ out) {
    __shared__ float lds[NFLOATS];
    __shared__ unsigned desc[612];  // byte offsets, 2448 B

    // bijective XCD swizzle: 2048 blocks, 8 XCDs, 256 contiguous per XCD
    unsigned bid = blockIdx.x;
    unsigned swz = (bid & 7u) * 256u + (bid >> 3);
    unsigned n = swz >> 6;    // image
    unsigned hp = swz & 63u;  // row pair
    unsigned h0 = hp * 2u;
    unsigned tid = threadIdx.x;

    // descriptor table (block-invariant): ii = (dw*17 + c)*9 + p,
    // value = byte offset of (c, hl, 3 + wl + dw); add g*16 (+560 slab1).
    for (unsigned ii = tid; ii < 612u; ii += 256u) {
        unsigned p = ii % 9u;
        unsigned t = ii / 9u;
        unsigned c = t % 17u;
        unsigned dw = t / 17u;
        unsigned hl = p / 3u;
        unsigned wl = p - hl * 3u;
        desc[ii] = (c * CSTRIDE + hl * RSTRIDE + 3u + wl + dw) * 4u;
    }

    // ones channel: fill channel 16 region with 1.0f
    for (unsigned li = tid; li < CSTRIDE; li += 256u)
        lds[16u * CSTRIDE + li] = 1.0f;

    // zero halo pads of the 64 real (c,hr) rows
    if (tid < 64u) {
        unsigned c = tid >> 2, hr = tid & 3u;
        lds[c * CSTRIDE + hr * RSTRIDE + 3] = 0.0f;
        lds[c * CSTRIDE + hr * RSTRIDE + 132] = 0.0f;
    }

    // stage: 64 rows x 32 float4 = 2048 float4, 8 per thread, coalesced
#pragma unroll
    for (int j = 0; j < 8; ++j) {
        unsigned li = tid + 256u * j;  // 0..2047
        unsigned row = li >> 5;        // 0..63 = c*4 + hr
        unsigned col = li & 31u;       // float4 column
        unsigned c = row >> 2;
        unsigned hr = row & 3u;
        int hh = (int)h0 + (int)hr - 1;
        f4 v = {0.f, 0.f, 0.f, 0.f};
        if ((unsigned)hh < (unsigned)HH) {
            v = reinterpret_cast<const f4*>(
                    x)[((n * CC + c) * HH + (unsigned)hh) * (WW / 4) + col];
        }
        *reinterpret_cast<f4*>(&lds[c * CSTRIDE + hr * RSTRIDE + 4u + col * 4u]) = v;
    }
    __syncthreads();

    const char* ldsb = reinterpret_cast<const char*>(lds);

    // fused epilogue: 4896 float4 positions, each written to BOTH slabs
    unsigned base0 = (n * 16384u + h0 * 128u) * 153u;
    f4* outp0 = reinterpret_cast<f4*>(out + base0);
    f4* outp1 = outp0 + 4896u;  // slab 1 = next h row, contiguous after
#pragma unroll 2
    for (unsigned q = tid; q < 4896u; q += 256u) {
        unsigned g = q / 153u;  // 4-pixel group (0..31)
        unsigned qm = q - g * 153u;
        unsigned wo = g * 16u;  // byte offset add-on, slab 0
        uint4 d4 = *reinterpret_cast<const uint4*>(&desc[qm * 4u]);
        f4 v0, v1;
        v0.x = *reinterpret_cast<const float*>(ldsb + (d4.x + wo));
        v0.y = *reinterpret_cast<const float*>(ldsb + (d4.y + wo));
        v0.z = *reinterpret_cast<const float*>(ldsb + (d4.z + wo));
        v0.w = *reinterpret_cast<const float*>(ldsb + (d4.w + wo));
        unsigned wo1 = wo + (RSTRIDE * 4u);  // slab 1: one h-row down
        v1.x = *reinterpret_cast<const float*>(ldsb + (d4.x + wo1));
        v1.y = *reinterpret_cast<const float*>(ldsb + (d4.y + wo1));
        v1.z = *reinterpret_cast<const float*>(ldsb + (d4.z + wo1));
        v1.w = *reinterpret_cast<const float*>(ldsb + (d4.w + wo1));
        __builtin_nontemporal_store(v0, &outp0[q]);
        __builtin_nontemporal_store(v1, &outp1[q]);
    }
}

extern "C" void kernel_launch(void* const* d_in, const int* in_sizes, int n_in,
                              void* d_out, int out_size, void* d_ws, size_t ws_size,
                              hipStream_t stream) {
    const float* x = (const float*)d_in[0];
    float* out = (float*)d_out;
    pve_kernel<<<NN * HH / 2, 256, 0, stream>>>(x, out);
}